// Round 1
// baseline (22835.252 us; speedup 1.0000x reference)
//
#include <hip/hip_runtime.h>
#include <math.h>

// KNRM-style ranker on MI355X, all-fp32 round-1 implementation.
// Workspace layout (floats): xq(2.10M) xd(16.78M) t0(16.78M) t1(16.78M)
//   qkv(CB*196608) h(FC*2048); CB/FC shrink if ws_size is small.
// Total at CB=64,FC=16384: ~394 MB; minimum (CB=8,FC=2048): ~233 MB.

#define DMODEL 256

// ---------------- embed + positional encoding ----------------
// x[tok,d] = 2*emb[id,d]*mask + pe(s,d)
__global__ __launch_bounds__(256) void k_embed(const int* __restrict__ ids,
    const float* __restrict__ emb, float* __restrict__ out_x, int S) {
  int tok = blockIdx.x;
  int d = threadIdx.x;
  int id = ids[tok];
  float m = id > 0 ? 1.f : 0.f;
  float e = emb[(size_t)id * DMODEL + d] * m;
  int s = tok % S;
  int i2 = d & ~1;
  float freq = expf((float)i2 * (-9.210340371976184f / 256.f)); // exp(-2i*ln(1e4)/256)
  float ang = (float)s * freq;
  float pe = (d & 1) ? cosf(ang) : sinf(ang);
  out_x[(size_t)tok * DMODEL + d] = 2.f * e + pe;
}

// ---------------- fp32 GEMM: out[M,N] = X[M,K] @ W[N,K]^T + bias (opt ReLU) ----------------
// 128x128 tile, 256 threads, 8x8 micro-tile split 4+4 for conflict-free b128 LDS reads.
// Requires M%128==0, N%128==0, K%16==0 (all shapes here satisfy this).
template<bool RELU>
__global__ __launch_bounds__(256) void k_gemm(const float* __restrict__ X,
    const float* __restrict__ W, const float* __restrict__ bias,
    float* __restrict__ out, int M, int N, int K) {
  __shared__ float As[16][128];
  __shared__ float Bs[16][128];
  int n0 = blockIdx.x * 128;
  int m0 = blockIdx.y * 128;
  int tid = threadIdx.x;
  int tx = tid & 15, ty = tid >> 4;
  float acc[8][8];
#pragma unroll
  for (int i = 0; i < 8; ++i)
#pragma unroll
    for (int j = 0; j < 8; ++j) acc[i][j] = 0.f;
  int lr = tid >> 1;
  int lk = (tid & 1) << 3;
  const float* Xp = X + (size_t)(m0 + lr) * K + lk;
  const float* Wp = W + (size_t)(n0 + lr) * K + lk;
  for (int kt = 0; kt < K; kt += 16) {
    float4 a0 = *(const float4*)(Xp + kt);
    float4 a1 = *(const float4*)(Xp + kt + 4);
    float4 b0 = *(const float4*)(Wp + kt);
    float4 b1 = *(const float4*)(Wp + kt + 4);
    __syncthreads();
    As[lk + 0][lr] = a0.x; As[lk + 1][lr] = a0.y; As[lk + 2][lr] = a0.z; As[lk + 3][lr] = a0.w;
    As[lk + 4][lr] = a1.x; As[lk + 5][lr] = a1.y; As[lk + 6][lr] = a1.z; As[lk + 7][lr] = a1.w;
    Bs[lk + 0][lr] = b0.x; Bs[lk + 1][lr] = b0.y; Bs[lk + 2][lr] = b0.z; Bs[lk + 3][lr] = b0.w;
    Bs[lk + 4][lr] = b1.x; Bs[lk + 5][lr] = b1.y; Bs[lk + 6][lr] = b1.z; Bs[lk + 7][lr] = b1.w;
    __syncthreads();
#pragma unroll
    for (int k = 0; k < 16; ++k) {
      float av[8], bv[8];
      *(float4*)&av[0] = *(const float4*)&As[k][ty * 4];
      *(float4*)&av[4] = *(const float4*)&As[k][64 + ty * 4];
      *(float4*)&bv[0] = *(const float4*)&Bs[k][tx * 4];
      *(float4*)&bv[4] = *(const float4*)&Bs[k][64 + tx * 4];
#pragma unroll
      for (int i = 0; i < 8; ++i)
#pragma unroll
        for (int j = 0; j < 8; ++j)
          acc[i][j] += av[i] * bv[j];
    }
  }
#pragma unroll
  for (int i = 0; i < 8; ++i) {
    int mr = m0 + ((i < 4) ? (ty * 4 + i) : (64 + ty * 4 + i - 4));
#pragma unroll
    for (int jb = 0; jb < 2; ++jb) {
      int nc = n0 + jb * 64 + tx * 4;
      float4 bz = *(const float4*)(bias + nc);
      float4 o4;
      o4.x = acc[i][jb * 4 + 0] + bz.x;
      o4.y = acc[i][jb * 4 + 1] + bz.y;
      o4.z = acc[i][jb * 4 + 2] + bz.z;
      o4.w = acc[i][jb * 4 + 3] + bz.w;
      if (RELU) {
        o4.x = fmaxf(o4.x, 0.f); o4.y = fmaxf(o4.y, 0.f);
        o4.z = fmaxf(o4.z, 0.f); o4.w = fmaxf(o4.w, 0.f);
      }
      *(float4*)(out + (size_t)mr * N + nc) = o4;
    }
  }
}

// ---------------- fused attention (online softmax), one block per (batch,head) ----------------
// 128 threads, NR rows per thread (NR=2 for S=256, NR=1 for S=32). K,V staged in LDS.
template<int NR>
__global__ __launch_bounds__(128) void k_attn(const float* __restrict__ qkv,
    float* __restrict__ o, int S, int b0) {
  __shared__ float Ks[256 * 32];
  __shared__ float Vs[256 * 32];
  int bl = blockIdx.x >> 3;
  int h = blockIdx.x & 7;
  int tid = threadIdx.x;
  const float* base = qkv + (size_t)bl * S * 768;
  int hc = h * 32;
  for (int f = tid; f < S * 32; f += 128) {
    int s = f >> 5, e = f & 31;
    Ks[f] = base[(size_t)s * 768 + 256 + hc + e];
    Vs[f] = base[(size_t)s * 768 + 512 + hc + e];
  }
  __syncthreads();
  if (tid >= S) return;  // only for S=32 (no barriers after this point)
  const float scale = 0.17677669529663687f;  // 1/sqrt(32)
  float q[NR][32], acc[NR][32], m[NR], l[NR];
#pragma unroll
  for (int r = 0; r < NR; ++r) {
    int row = tid + 128 * r;
    const float4* qp = (const float4*)(base + (size_t)row * 768 + hc);
#pragma unroll
    for (int w = 0; w < 8; ++w) {
      float4 t = qp[w];
      q[r][4 * w] = t.x; q[r][4 * w + 1] = t.y; q[r][4 * w + 2] = t.z; q[r][4 * w + 3] = t.w;
    }
    m[r] = -1e30f; l[r] = 0.f;
#pragma unroll
    for (int e = 0; e < 32; ++e) acc[r][e] = 0.f;
  }
  for (int j = 0; j < S; ++j) {
    float kv[32];
    const float4* kp = (const float4*)&Ks[j * 32];
#pragma unroll
    for (int w = 0; w < 8; ++w) {
      float4 t = kp[w];
      kv[4 * w] = t.x; kv[4 * w + 1] = t.y; kv[4 * w + 2] = t.z; kv[4 * w + 3] = t.w;
    }
    float p[NR];
#pragma unroll
    for (int r = 0; r < NR; ++r) {
      float dot = 0.f;
#pragma unroll
      for (int e = 0; e < 32; ++e) dot += q[r][e] * kv[e];
      float s_ = dot * scale;
      float mn = fmaxf(m[r], s_);
      p[r] = __expf(s_ - mn);
      if (mn > m[r]) {
        float al = __expf(m[r] - mn);
        l[r] *= al;
#pragma unroll
        for (int e = 0; e < 32; ++e) acc[r][e] *= al;
        m[r] = mn;
      }
      l[r] += p[r];
    }
    const float4* vp = (const float4*)&Vs[j * 32];
#pragma unroll
    for (int w = 0; w < 8; ++w) {
      float4 t = vp[w];
#pragma unroll
      for (int r = 0; r < NR; ++r) {
        acc[r][4 * w]     += p[r] * t.x;
        acc[r][4 * w + 1] += p[r] * t.y;
        acc[r][4 * w + 2] += p[r] * t.z;
        acc[r][4 * w + 3] += p[r] * t.w;
      }
    }
  }
#pragma unroll
  for (int r = 0; r < NR; ++r) {
    int row = tid + 128 * r;
    float inv = 1.f / l[r];
    float4* op = (float4*)(o + ((size_t)(b0 + bl) * S + row) * DMODEL + hc);
#pragma unroll
    for (int w = 0; w < 8; ++w) {
      float4 t;
      t.x = acc[r][4 * w] * inv;     t.y = acc[r][4 * w + 1] * inv;
      t.z = acc[r][4 * w + 2] * inv; t.w = acc[r][4 * w + 3] * inv;
      op[w] = t;
    }
  }
}

// ---------------- residual add + LayerNorm, one wave per token ----------------
__global__ __launch_bounds__(64) void k_addln(float* __restrict__ x,
    const float* __restrict__ t, const float* __restrict__ sc,
    const float* __restrict__ bi) {
  size_t tok = blockIdx.x;
  int tid = threadIdx.x;
  float4 xv = *(const float4*)(x + tok * 256 + tid * 4);
  float4 tv = *(const float4*)(t + tok * 256 + tid * 4);
  float4 v;
  v.x = xv.x + tv.x; v.y = xv.y + tv.y; v.z = xv.z + tv.z; v.w = xv.w + tv.w;
  float s1 = v.x + v.y + v.z + v.w;
#pragma unroll
  for (int o = 32; o > 0; o >>= 1) s1 += __shfl_xor(s1, o);
  float mean = s1 * (1.f / 256.f);
  float dx = v.x - mean, dy = v.y - mean, dz = v.z - mean, dw = v.w - mean;
  float s2 = dx * dx + dy * dy + dz * dz + dw * dw;
#pragma unroll
  for (int o = 32; o > 0; o >>= 1) s2 += __shfl_xor(s2, o);
  float rs = rsqrtf(s2 * (1.f / 256.f) + 1e-5f);
  float4 s4 = *(const float4*)(sc + tid * 4);
  float4 b4 = *(const float4*)(bi + tid * 4);
  float4 ov;
  ov.x = dx * rs * s4.x + b4.x;
  ov.y = dy * rs * s4.y + b4.y;
  ov.z = dz * rs * s4.z + b4.z;
  ov.w = dw * rs * s4.w + b4.w;
  *(float4*)(x + tok * 256 + tid * 4) = ov;
}

// ---------------- fused scoring: sim -> RBF kernels -> log/len pooling -> mlp ----------------
// One block per batch b; thread j owns doc position j; q_mix staged in LDS.
__global__ __launch_bounds__(256) void k_score(
    const int* __restrict__ qids, const int* __restrict__ dids,
    const float* __restrict__ emb, const float* __restrict__ xq,
    const float* __restrict__ xd, const float* __restrict__ a_ptr,
    const float* __restrict__ mlp_w, float* __restrict__ out) {
  __shared__ float qmix[32 * 256];
  __shared__ float qks[32 * 11];
  __shared__ float qmask_s[32];
  int b = blockIdx.x, tid = threadIdx.x;
  float av = a_ptr[0], aw = 1.f - av;
  for (int q = 0; q < 32; ++q) {
    int qid = qids[b * 32 + q];
    float qm = qid > 0 ? 1.f : 0.f;
    float ev = emb[(size_t)qid * 256 + tid];          // emb[id]*mask folded via qm^2==qm
    float xv = xq[((size_t)b * 32 + q) * 256 + tid];
    qmix[q * 256 + tid] = (av * ev + aw * xv) * qm;
    if (tid == 0) qmask_s[q] = qm;
  }
  for (int i = tid; i < 352; i += 256) qks[i] = 0.f;
  __syncthreads();
  int j = tid;
  int did = dids[b * 256 + j];
  float dmask = did > 0 ? 1.f : 0.f;
  float sim[32];
#pragma unroll
  for (int q = 0; q < 32; ++q) sim[q] = 0.f;
  const float4* de = (const float4*)(emb + (size_t)did * 256);
  const float4* dxp = (const float4*)(xd + ((size_t)b * 256 + j) * 256);
  for (int c = 0; c < 4; ++c) {
    float4 dreg[16];
#pragma unroll
    for (int w = 0; w < 16; ++w) {
      float4 e = de[c * 16 + w], x = dxp[c * 16 + w];
      dreg[w].x = av * e.x + aw * x.x;
      dreg[w].y = av * e.y + aw * x.y;
      dreg[w].z = av * e.z + aw * x.z;
      dreg[w].w = av * e.w + aw * x.w;
    }
#pragma unroll
    for (int q = 0; q < 32; ++q) {
      const float4* qp = (const float4*)&qmix[q * 256 + c * 64];
      float d_ = 0.f;
#pragma unroll
      for (int w = 0; w < 16; ++w) {
        float4 t = qp[w];
        d_ += t.x * dreg[w].x + t.y * dreg[w].y + t.z * dreg[w].z + t.w * dreg[w].w;
      }
      sim[q] += d_;
    }
  }
  const float MU[11] = {1.f, 0.9f, 0.7f, 0.5f, 0.3f, 0.1f, -0.1f, -0.3f, -0.5f, -0.7f, -0.9f};
  const float IC[11] = {5e7f, 50.f, 50.f, 50.f, 50.f, 50.f, 50.f, 50.f, 50.f, 50.f, 50.f};
  for (int q = 0; q < 32; ++q) {
    float s = sim[q];
    float f = dmask * qmask_s[q];
#pragma unroll
    for (int k = 0; k < 11; ++k) {
      float d_ = s - MU[k];
      float v = expf(-d_ * d_ * IC[k]) * f;
#pragma unroll
      for (int o = 32; o > 0; o >>= 1) v += __shfl_xor(v, o);
      if ((tid & 63) == 0) atomicAdd(&qks[q * 11 + k], v);
    }
  }
  __syncthreads();
  if (tid < 32) {
    float qm = qmask_s[tid];
    float p = 0.f;
#pragma unroll
    for (int k = 0; k < 11; ++k) {
      float qv = qks[tid * 11 + k];
      p += mlp_w[k] * (qm * logf(fmaxf(qv, 1e-10f)) + qv * (1.f / 256.f));
    }
#pragma unroll
    for (int o = 16; o > 0; o >>= 1) p += __shfl_xor(p, o);
    if (tid == 0) out[b] = p;
  }
}

// ---------------- host-side encoder schedule ----------------
static void run_encoder(float* x, int S, int B, int CB, int FC,
    const float* Wqkv, const float* bqkv, const float* Wo, const float* bo,
    const float* l1s, const float* l1b, const float* W1, const float* b1,
    const float* W2, const float* b2, const float* l2s, const float* l2b,
    float* qkv, float* t0, float* t1, float* h, hipStream_t stream) {
  int tokens = B * S;
  int nchunk = B / CB;
  for (int l = 0; l < 2; ++l) {
    const float* wq = Wqkv + (size_t)l * 768 * 256;
    const float* bq = bqkv + l * 768;
    const float* wo = Wo + (size_t)l * 256 * 256;
    const float* bo_ = bo + l * 256;
    const float* w1 = W1 + (size_t)l * 2048 * 256;
    const float* b1_ = b1 + l * 2048;
    const float* w2 = W2 + (size_t)l * 256 * 2048;
    const float* b2_ = b2 + l * 256;
    for (int c = 0; c < nchunk; ++c) {
      float* xc = x + (size_t)c * CB * S * 256;
      int Mc = CB * S;
      k_gemm<false><<<dim3(768 / 128, Mc / 128), 256, 0, stream>>>(xc, wq, bq, qkv, Mc, 768, 256);
      if (S == 256)
        k_attn<2><<<CB * 8, 128, 0, stream>>>(qkv, t0, S, c * CB);
      else
        k_attn<1><<<CB * 8, 128, 0, stream>>>(qkv, t0, S, c * CB);
    }
    k_gemm<false><<<dim3(256 / 128, tokens / 128), 256, 0, stream>>>(t0, wo, bo_, t1, tokens, 256, 256);
    k_addln<<<tokens, 64, 0, stream>>>(x, t1, l1s + l * 256, l1b + l * 256);
    for (int f = 0; f < tokens; f += FC) {
      int Mc = (tokens - f < FC) ? (tokens - f) : FC;
      k_gemm<true><<<dim3(2048 / 128, Mc / 128), 256, 0, stream>>>(x + (size_t)f * 256, w1, b1_, h, Mc, 2048, 256);
      k_gemm<false><<<dim3(256 / 128, Mc / 128), 256, 0, stream>>>(h, w2, b2_, t1 + (size_t)f * 256, Mc, 256, 2048);
    }
    k_addln<<<tokens, 64, 0, stream>>>(x, t1, l2s + l * 256, l2b + l * 256);
  }
}

extern "C" void kernel_launch(void* const* d_in, const int* in_sizes, int n_in,
                              void* d_out, int out_size, void* d_ws, size_t ws_size,
                              hipStream_t stream) {
  const int* qids = (const int*)d_in[0];
  const int* dids = (const int*)d_in[1];
  const float* emb = (const float*)d_in[2];
  const float* a = (const float*)d_in[3];
  const float* mlp_w = (const float*)d_in[4];
  const float* Wqkv = (const float*)d_in[5];
  const float* bqkv = (const float*)d_in[6];
  const float* Wo = (const float*)d_in[7];
  const float* bo = (const float*)d_in[8];
  const float* l1s = (const float*)d_in[9];
  const float* l1b = (const float*)d_in[10];
  const float* W1 = (const float*)d_in[11];
  const float* b1 = (const float*)d_in[12];
  const float* W2 = (const float*)d_in[13];
  const float* b2 = (const float*)d_in[14];
  const float* l2s = (const float*)d_in[15];
  const float* l2b = (const float*)d_in[16];
  float* out = (float*)d_out;
  float* ws = (float*)d_ws;

  size_t wsf = ws_size / 4;  // floats available
  float* xq = ws;                    // 256*32*256
  float* xd = xq + 2097152;          // 256*256*256
  float* t0 = xd + 16777216;
  float* t1 = t0 + 16777216;
  float* qkv = t1 + 16777216;
  const size_t fixed = 2097152 + 3 * 16777216UL;
  int CB = 64, FC = 16384;  // batches/qkv-chunk, tokens/ffn-chunk
  while (CB > 8 && fixed + (size_t)CB * 196608 + (size_t)FC * 2048 > wsf) CB >>= 1;
  while (FC > 2048 && fixed + (size_t)CB * 196608 + (size_t)FC * 2048 > wsf) FC >>= 1;
  float* h = qkv + (size_t)CB * 196608;

  // 1) embedding gather + 2x + positional encoding
  k_embed<<<256 * 32, 256, 0, stream>>>(qids, emb, xq, 32);
  k_embed<<<256 * 256, 256, 0, stream>>>(dids, emb, xd, 256);

  // 2) encoders (doc then query, sharing scratch)
  run_encoder(xd, 256, 256, CB, FC, Wqkv, bqkv, Wo, bo, l1s, l1b, W1, b1,
              W2, b2, l2s, l2b, qkv, t0, t1, h, stream);
  int CBq = CB * 8; if (CBq > 256) CBq = 256;
  run_encoder(xq, 32, 256, CBq, FC, Wqkv, bqkv, Wo, bo, l1s, l1b, W1, b1,
              W2, b2, l2s, l2b, qkv, t0, t1, h, stream);

  // 3) fused similarity + RBF kernel pooling + score
  k_score<<<256, 256, 0, stream>>>(qids, dids, emb, xq, xd, a, mlp_w, out);
}